// Round 2
// baseline (4527.938 us; speedup 1.0000x reference)
//
#include <hip/hip_runtime.h>
#include <string.h>

// Problem constants
constexpr int Bc   = 4;
constexpr int Nc   = 16384;
constexpr int Ec   = 131072;   // 2^17
constexpr int Hc   = 8;
constexpr int Dc   = 16;
constexpr int HIDc = 128;

// DTYPE NOTE (R1 post-mortem): inputs/outputs are FLOAT32 per the reference
// (jnp.float32 everywhere). Reading them as bf16 in R1 decoded mantissa bits
// as bf16 -> ~0.4% NaN patterns -> NaN output. Internal intermediates
// (Q/K/V/h1/mid, LDS weight tiles) are bf16 for bandwidth; accumulation f32.

// ---------- helpers ----------
__device__ inline float b2f(unsigned short u) {
    return __uint_as_float(((unsigned)u) << 16);
}
__device__ inline unsigned short f2b(float f) {
    unsigned b = __float_as_uint(f);
    unsigned r = (b + 0x7FFFu + ((b >> 16) & 1u)) >> 16;  // RNE
    return (unsigned short)r;
}
// monotone float<->uint map for atomicMax on floats
__device__ inline unsigned f2o(float f) {
    unsigned b = __float_as_uint(f);
    return (b & 0x80000000u) ? ~b : (b | 0x80000000u);
}
__device__ inline float o2f(unsigned u) {
    return __uint_as_float((u & 0x80000000u) ? (u ^ 0x80000000u) : ~u);
}
// load 16 consecutive bf16 (32B aligned) -> 16 floats
__device__ inline void load16(const unsigned short* __restrict__ p, float* f) {
    const uint4* p4 = (const uint4*)p;
    uint4 a = p4[0], b = p4[1];
    unsigned v[8] = {a.x, a.y, a.z, a.w, b.x, b.y, b.z, b.w};
#pragma unroll
    for (int i = 0; i < 8; ++i) {
        f[2 * i]     = __uint_as_float(v[i] << 16);
        f[2 * i + 1] = __uint_as_float(v[i] & 0xFFFF0000u);
    }
}
// stage f32 weight matrix (nElem floats) into LDS as bf16
__device__ inline void stage_w_bf16(unsigned short* __restrict__ w,
                                    const float* __restrict__ src, int nVec4) {
    for (int i = threadIdx.x; i < nVec4; i += 256) {
        float4 f = ((const float4*)src)[i];
        ushort4 u;
        u.x = f2b(f.x); u.y = f2b(f.y); u.z = f2b(f.z); u.w = f2b(f.w);
        ((ushort4*)w)[i] = u;
    }
}

// ---------- init: zero accumulators, set nodemax = ord(-1e9) ----------
__global__ __launch_bounds__(256) void k_init(unsigned* __restrict__ nodemax,
                                              float* __restrict__ denom,
                                              float* __restrict__ attn,
                                              unsigned ordneg) {
    int i = blockIdx.x * 256 + threadIdx.x;           // grid covers Bc*Nc*HIDc
    attn[i] = 0.f;
    if (i < Bc * Nc * Hc) { nodemax[i] = ordneg; denom[i] = 0.f; }
}

// ---------- QKV: one weight (128x128) per blockIdx.y, wave-per-row ----------
__global__ __launch_bounds__(256) void k_qkv(const float* __restrict__ hin,
                                             const float* __restrict__ Wq,
                                             const float* __restrict__ Wk,
                                             const float* __restrict__ Wv,
                                             unsigned short* __restrict__ Q,
                                             unsigned short* __restrict__ K,
                                             unsigned short* __restrict__ V) {
    __shared__ unsigned short w[16384];  // 128x128 bf16 = 32KB
    const float* Wsel = (blockIdx.y == 0) ? Wq : ((blockIdx.y == 1) ? Wk : Wv);
    stage_w_bf16(w, Wsel, 4096);
    __syncthreads();
    int wave = threadIdx.x >> 6, lane = threadIdx.x & 63;
    size_t row = (size_t)blockIdx.x * 4 + wave;
    float x0 = hin[row * 128 + lane];
    float x1 = hin[row * 128 + 64 + lane];
    float acc0 = 0.f, acc1 = 0.f;
#pragma unroll 1
    for (int half = 0; half < 2; ++half) {
        float xs = half ? x1 : x0;
        for (int k2 = 0; k2 < 64; ++k2) {
            float xb = __shfl(xs, k2, 64);
            int k = half * 64 + k2;
            acc0 += xb * b2f(w[(k << 7) + lane]);
            acc1 += xb * b2f(w[(k << 7) + 64 + lane]);
        }
    }
    unsigned short* O = (blockIdx.y == 0) ? Q : ((blockIdx.y == 1) ? K : V);
    O[row * 128 + lane]      = f2b(acc0);
    O[row * 128 + 64 + lane] = f2b(acc1);
}

// ---------- edge logits + atomic max into nodemax ----------
__global__ __launch_bounds__(256) void k_logits(const unsigned short* __restrict__ Q,
                                                const unsigned short* __restrict__ K,
                                                const float* __restrict__ ef,
                                                const int* __restrict__ eidx,
                                                const int* __restrict__ nedges,
                                                const float* __restrict__ We,
                                                float* __restrict__ logits,
                                                unsigned* __restrict__ nodemax) {
    int t = blockIdx.x * 256 + threadIdx.x;  // [0, B*E*H)
    int hh = t & 7;
    int eh = t >> 3;          // b*E + e
    int b = eh >> 17;
    int e = eh & (Ec - 1);
    if (e >= nedges[b]) { logits[t] = -1e30f; return; }
    int src = eidx[(size_t)(b * 2) * Ec + e];
    int dst = eidx[(size_t)(b * 2 + 1) * Ec + e];
    float q[16], kk[16];
    load16(Q + ((size_t)b * Nc + dst) * 128 + hh * 16, q);
    load16(K + ((size_t)b * Nc + src) * 128 + hh * 16, kk);
    float dot = 0.f;
#pragma unroll
    for (int d = 0; d < 16; ++d) dot += q[d] * kk[d];
    float e0 = ef[(size_t)eh * 2];
    float e1 = ef[(size_t)eh * 2 + 1];
    float lg = 0.25f * dot + e0 * We[hh] + e1 * We[8 + hh];
    logits[t] = lg;
    atomicMax(&nodemax[((size_t)b * Nc + dst) * 8 + hh], f2o(lg));
}

// ---------- p = exp(lg - max), denom += p ----------
__global__ __launch_bounds__(256) void k_softmax_p(const int* __restrict__ eidx,
                                                   const int* __restrict__ nedges,
                                                   float* __restrict__ logits,
                                                   const unsigned* __restrict__ nodemax,
                                                   float* __restrict__ denom) {
    int t = blockIdx.x * 256 + threadIdx.x;
    int hh = t & 7;
    int eh = t >> 3;
    int b = eh >> 17;
    int e = eh & (Ec - 1);
    if (e >= nedges[b]) return;
    int dst = eidx[(size_t)(b * 2 + 1) * Ec + e];
    float m = o2f(nodemax[((size_t)b * Nc + dst) * 8 + hh]);
    float p = __expf(logits[t] - m);
    logits[t] = p;
    atomicAdd(&denom[((size_t)b * Nc + dst) * 8 + hh], p);
}

// ---------- attn[dst] += (p/denom[dst]) * V[src] ----------
__global__ __launch_bounds__(256) void k_scatter(const int* __restrict__ eidx,
                                                 const int* __restrict__ nedges,
                                                 const float* __restrict__ logits,
                                                 const float* __restrict__ denom,
                                                 const unsigned short* __restrict__ V,
                                                 float* __restrict__ attn) {
    int t = blockIdx.x * 256 + threadIdx.x;
    int hh = t & 7;
    int eh = t >> 3;
    int b = eh >> 17;
    int e = eh & (Ec - 1);
    if (e >= nedges[b]) return;
    int src = eidx[(size_t)(b * 2) * Ec + e];
    int dst = eidx[(size_t)(b * 2 + 1) * Ec + e];
    float p = logits[t];
    float alpha = p / fmaxf(denom[((size_t)b * Nc + dst) * 8 + hh], 1e-6f);
    float v[16];
    load16(V + ((size_t)b * Nc + src) * 128 + hh * 16, v);
    float* o = attn + ((size_t)b * Nc + dst) * 128 + hh * 16;
#pragma unroll
    for (int d = 0; d < 16; ++d) atomicAdd(&o[d], alpha * v[d]);
}

// ---------- out@Wo + bo + h  -> LN1 -> h1 (bf16) ----------
__global__ __launch_bounds__(256) void k_wo_ln(const float* __restrict__ attn,
                                               const float* __restrict__ Wo,
                                               const float* __restrict__ bo,
                                               const float* __restrict__ hin,
                                               const float* __restrict__ g,
                                               const float* __restrict__ bb,
                                               unsigned short* __restrict__ h1) {
    __shared__ unsigned short w[16384];
    stage_w_bf16(w, Wo, 4096);
    __syncthreads();
    int wave = threadIdx.x >> 6, lane = threadIdx.x & 63;
    size_t row = (size_t)blockIdx.x * 4 + wave;
    const float* a = attn + row * 128;
    float x0 = a[lane], x1 = a[64 + lane];
    float acc0 = 0.f, acc1 = 0.f;
#pragma unroll 1
    for (int half = 0; half < 2; ++half) {
        float xs = half ? x1 : x0;
        for (int k2 = 0; k2 < 64; ++k2) {
            float xb = __shfl(xs, k2, 64);
            int k = half * 64 + k2;
            acc0 += xb * b2f(w[(k << 7) + lane]);
            acc1 += xb * b2f(w[(k << 7) + 64 + lane]);
        }
    }
    acc0 += bo[lane]      + hin[row * 128 + lane];
    acc1 += bo[64 + lane] + hin[row * 128 + 64 + lane];
    float s1 = acc0 + acc1, s2 = acc0 * acc0 + acc1 * acc1;
#pragma unroll
    for (int o = 32; o > 0; o >>= 1) { s1 += __shfl_xor(s1, o, 64); s2 += __shfl_xor(s2, o, 64); }
    float mean = s1 * (1.f / 128.f);
    float var  = s2 * (1.f / 128.f) - mean * mean;
    float rstd = rsqrtf(var + 1e-5f);
    h1[row * 128 + lane]      = f2b((acc0 - mean) * rstd * g[lane] + bb[lane]);
    h1[row * 128 + 64 + lane] = f2b((acc1 - mean) * rstd * g[64 + lane] + bb[64 + lane]);
}

// ---------- mid = relu(h1@ff1 + b1) (bf16) ----------
__global__ __launch_bounds__(256) void k_ff1(const unsigned short* __restrict__ h1,
                                             const float* __restrict__ ff1,
                                             const float* __restrict__ b1,
                                             unsigned short* __restrict__ mid) {
    __shared__ unsigned short w[32768];  // 128x256 bf16 = 64KB
    stage_w_bf16(w, ff1, 8192);
    __syncthreads();
    int wave = threadIdx.x >> 6, lane = threadIdx.x & 63;
    size_t row = (size_t)blockIdx.x * 4 + wave;
    float x0 = b2f(h1[row * 128 + lane]);
    float x1 = b2f(h1[row * 128 + 64 + lane]);
    float acc[4] = {0.f, 0.f, 0.f, 0.f};
#pragma unroll 1
    for (int half = 0; half < 2; ++half) {
        float xs = half ? x1 : x0;
        for (int k2 = 0; k2 < 64; ++k2) {
            float xb = __shfl(xs, k2, 64);
            int k = half * 64 + k2;
#pragma unroll
            for (int j = 0; j < 4; ++j) acc[j] += xb * b2f(w[(k << 8) + (j << 6) + lane]);
        }
    }
#pragma unroll
    for (int j = 0; j < 4; ++j) {
        int c = (j << 6) + lane;
        mid[row * 256 + c] = f2b(fmaxf(acc[j] + b1[c], 0.f));
    }
}

// ---------- mid@ff2 + b2 + h1 -> LN2 -> out (f32) ----------
__global__ __launch_bounds__(256) void k_ff2_ln(const unsigned short* __restrict__ mid,
                                                const float* __restrict__ ff2,
                                                const float* __restrict__ b2p,
                                                const unsigned short* __restrict__ h1,
                                                const float* __restrict__ g,
                                                const float* __restrict__ bb,
                                                float* __restrict__ out) {
    __shared__ unsigned short w[32768];  // 256x128 bf16 = 64KB
    stage_w_bf16(w, ff2, 8192);
    __syncthreads();
    int wave = threadIdx.x >> 6, lane = threadIdx.x & 63;
    size_t row = (size_t)blockIdx.x * 4 + wave;
    float xs4[4];
#pragma unroll
    for (int j = 0; j < 4; ++j) xs4[j] = b2f(mid[row * 256 + (j << 6) + lane]);
    float acc0 = 0.f, acc1 = 0.f;
#pragma unroll 1
    for (int q = 0; q < 4; ++q) {
        float xs = xs4[q];
        for (int k2 = 0; k2 < 64; ++k2) {
            float xb = __shfl(xs, k2, 64);
            int k = (q << 6) + k2;
            acc0 += xb * b2f(w[(k << 7) + lane]);
            acc1 += xb * b2f(w[(k << 7) + 64 + lane]);
        }
    }
    acc0 += b2p[lane]      + b2f(h1[row * 128 + lane]);
    acc1 += b2p[64 + lane] + b2f(h1[row * 128 + 64 + lane]);
    float s1 = acc0 + acc1, s2 = acc0 * acc0 + acc1 * acc1;
#pragma unroll
    for (int o = 32; o > 0; o >>= 1) { s1 += __shfl_xor(s1, o, 64); s2 += __shfl_xor(s2, o, 64); }
    float mean = s1 * (1.f / 128.f);
    float var  = s2 * (1.f / 128.f) - mean * mean;
    float rstd = rsqrtf(var + 1e-5f);
    out[row * 128 + lane]      = (acc0 - mean) * rstd * g[lane] + bb[lane];
    out[row * 128 + 64 + lane] = (acc1 - mean) * rstd * g[64 + lane] + bb[64 + lane];
}

extern "C" void kernel_launch(void* const* d_in, const int* in_sizes, int n_in,
                              void* d_out, int out_size, void* d_ws, size_t ws_size,
                              hipStream_t stream) {
    const float* h    = (const float*)d_in[0];
    const float* ef   = (const float*)d_in[1];
    const int*   eidx = (const int*)d_in[2];
    const int*   ne   = (const int*)d_in[3];
    const float* Wq   = (const float*)d_in[4];
    const float* Wk   = (const float*)d_in[5];
    const float* Wv   = (const float*)d_in[6];
    const float* Wo   = (const float*)d_in[7];
    const float* bo   = (const float*)d_in[8];
    const float* We   = (const float*)d_in[9];
    const float* ln1g = (const float*)d_in[10];
    const float* ln1b = (const float*)d_in[11];
    const float* ln2g = (const float*)d_in[12];
    const float* ln2b = (const float*)d_in[13];
    const float* ff1  = (const float*)d_in[14];
    const float* b1   = (const float*)d_in[15];
    const float* ff2  = (const float*)d_in[16];
    const float* b2   = (const float*)d_in[17];

    constexpr size_t MB = 1024 * 1024;
    char* ws = (char*)d_ws;
    unsigned short* Q       = (unsigned short*)(ws + 0 * MB);    // 16 MB bf16
    unsigned short* Kp      = (unsigned short*)(ws + 16 * MB);   // 16 MB bf16
    unsigned short* V       = (unsigned short*)(ws + 32 * MB);   // 16 MB bf16
    float*          logits  = (float*)(ws + 48 * MB);            // 16 MB f32 (B*E*H)
    unsigned*       nodemax = (unsigned*)(ws + 64 * MB);         // 2 MB
    float*          denom   = (float*)(ws + 66 * MB);            // 2 MB
    float*          attn    = (float*)(ws + 68 * MB);            // 32 MB f32 (B*N*HID)
    unsigned short* h1      = (unsigned short*)(ws + 100 * MB);  // 16 MB bf16
    unsigned short* mid     = (unsigned short*)(ws + 116 * MB);  // 32 MB bf16 (B*N*256)

    // ordered-uint encoding of -1e9f (host-side)
    float negv = -1e9f;
    unsigned bits; memcpy(&bits, &negv, 4);
    unsigned ordneg = (bits & 0x80000000u) ? ~bits : (bits | 0x80000000u);

    const int rowBlocks  = (Bc * Nc) / 4;          // 16384
    const int edgeBlocks = (Bc * Ec * Hc) / 256;   // 16384
    const int initBlocks = (Bc * Nc * HIDc) / 256; // 32768

    k_init<<<initBlocks, 256, 0, stream>>>(nodemax, denom, attn, ordneg);
    k_qkv<<<dim3(rowBlocks, 3), 256, 0, stream>>>(h, Wq, Wk, Wv, Q, Kp, V);
    k_logits<<<edgeBlocks, 256, 0, stream>>>(Q, Kp, ef, eidx, ne, We, logits, nodemax);
    k_softmax_p<<<edgeBlocks, 256, 0, stream>>>(eidx, ne, logits, nodemax, denom);
    k_scatter<<<edgeBlocks, 256, 0, stream>>>(eidx, ne, logits, denom, V, attn);
    k_wo_ln<<<rowBlocks, 256, 0, stream>>>(attn, Wo, bo, h, ln1g, ln1b, h1);
    k_ff1<<<rowBlocks, 256, 0, stream>>>(h1, ff1, b1, mid);
    k_ff2_ln<<<rowBlocks, 256, 0, stream>>>(mid, ff2, b2, h1, ln2g, ln2b,
                                            (float*)d_out);
}

// Round 3
// 1466.104 us; speedup vs baseline: 3.0884x; 3.0884x over previous
//
#include <hip/hip_runtime.h>
#include <string.h>

// Problem constants
constexpr int Bc   = 4;
constexpr int Nc   = 16384;
constexpr int Ec   = 131072;   // 2^17
constexpr int Hc   = 8;
constexpr int Dc   = 16;
constexpr int HIDc = 128;
constexpr int BN   = Bc * Nc;  // 65536

// R2 post-mortem: 67M device-scope f32 atomicAdds in k_scatter = 3000us,
// 1.66GB HBM write traffic (atomics punch through non-coherent per-XCD L2
// to the common point). R3: CSR bucket-by-dst + per-node online-softmax
// gather in registers -> zero atomics in the hot phase.

// ---------- helpers ----------
__device__ inline float b2f(unsigned short u) {
    return __uint_as_float(((unsigned)u) << 16);
}
__device__ inline unsigned short f2b(float f) {
    unsigned b = __float_as_uint(f);
    unsigned r = (b + 0x7FFFu + ((b >> 16) & 1u)) >> 16;  // RNE
    return (unsigned short)r;
}
// stage f32 weight matrix into LDS as bf16
__device__ inline void stage_w_bf16(unsigned short* __restrict__ w,
                                    const float* __restrict__ src, int nVec4) {
    for (int i = threadIdx.x; i < nVec4; i += 256) {
        float4 f = ((const float4*)src)[i];
        ushort4 u;
        u.x = f2b(f.x); u.y = f2b(f.y); u.z = f2b(f.z); u.w = f2b(f.w);
        ((ushort4*)w)[i] = u;
    }
}

// ---------- init: zero histogram counters ----------
__global__ __launch_bounds__(256) void k_init(unsigned* __restrict__ counts) {
    int i = blockIdx.x * 256 + threadIdx.x;   // grid covers BN
    counts[i] = 0u;
}

// ---------- QKV: one weight (128x128) per blockIdx.y, wave-per-row ----------
__global__ __launch_bounds__(256) void k_qkv(const float* __restrict__ hin,
                                             const float* __restrict__ Wq,
                                             const float* __restrict__ Wk,
                                             const float* __restrict__ Wv,
                                             unsigned short* __restrict__ Q,
                                             unsigned short* __restrict__ K,
                                             unsigned short* __restrict__ V) {
    __shared__ unsigned short w[16384];  // 128x128 bf16 = 32KB
    const float* Wsel = (blockIdx.y == 0) ? Wq : ((blockIdx.y == 1) ? Wk : Wv);
    stage_w_bf16(w, Wsel, 4096);
    __syncthreads();
    int wave = threadIdx.x >> 6, lane = threadIdx.x & 63;
    size_t row = (size_t)blockIdx.x * 4 + wave;
    float x0 = hin[row * 128 + lane];
    float x1 = hin[row * 128 + 64 + lane];
    float acc0 = 0.f, acc1 = 0.f;
#pragma unroll 1
    for (int half = 0; half < 2; ++half) {
        float xs = half ? x1 : x0;
        for (int k2 = 0; k2 < 64; ++k2) {
            float xb = __shfl(xs, k2, 64);
            int k = half * 64 + k2;
            acc0 += xb * b2f(w[(k << 7) + lane]);
            acc1 += xb * b2f(w[(k << 7) + 64 + lane]);
        }
    }
    unsigned short* O = (blockIdx.y == 0) ? Q : ((blockIdx.y == 1) ? K : V);
    O[row * 128 + lane]      = f2b(acc0);
    O[row * 128 + 64 + lane] = f2b(acc1);
}

// ---------- CSR build: histogram of dst ----------
__global__ __launch_bounds__(256) void k_hist(const int* __restrict__ eidx,
                                              const int* __restrict__ nedges,
                                              unsigned* __restrict__ counts) {
    int t = blockIdx.x * 256 + threadIdx.x;   // [0, B*E)
    int b = t >> 17;
    int e = t & (Ec - 1);
    if (e >= nedges[b]) return;
    int dst = eidx[(size_t)(b * 2 + 1) * Ec + e];
    atomicAdd(&counts[b * Nc + dst], 1u);
}

// ---------- scan step 1: per-block (256) exclusive scan + block sums ----------
__global__ __launch_bounds__(256) void k_scan1(const unsigned* __restrict__ counts,
                                               unsigned* __restrict__ rowptr,
                                               unsigned* __restrict__ bsum) {
    __shared__ unsigned s[256];
    int t = threadIdx.x;
    int i = blockIdx.x * 256 + t;
    unsigned own = counts[i];
    s[t] = own;
    __syncthreads();
#pragma unroll
    for (int off = 1; off < 256; off <<= 1) {
        unsigned v = (t >= off) ? s[t - off] : 0u;
        __syncthreads();
        s[t] += v;
        __syncthreads();
    }
    rowptr[i] = s[t] - own;            // exclusive within block
    if (t == 255) bsum[blockIdx.x] = s[255];
}

// ---------- scan step 2: exclusive scan of 256 block sums ----------
__global__ __launch_bounds__(256) void k_scan2(unsigned* __restrict__ bsum) {
    __shared__ unsigned s[256];
    int t = threadIdx.x;
    unsigned own = bsum[t];
    s[t] = own;
    __syncthreads();
#pragma unroll
    for (int off = 1; off < 256; off <<= 1) {
        unsigned v = (t >= off) ? s[t - off] : 0u;
        __syncthreads();
        s[t] += v;
        __syncthreads();
    }
    bsum[t] = s[t] - own;
}

// ---------- scan step 3: add block offsets, copy to cursor, set tail ----------
__global__ __launch_bounds__(256) void k_scan3(unsigned* __restrict__ rowptr,
                                               const unsigned* __restrict__ bsum,
                                               const unsigned* __restrict__ counts,
                                               unsigned* __restrict__ cursor) {
    int i = blockIdx.x * 256 + threadIdx.x;
    unsigned v = rowptr[i] + bsum[blockIdx.x];
    rowptr[i] = v;
    cursor[i] = v;
    if (i == BN - 1) rowptr[BN] = v + counts[i];
}

// ---------- CSR fill ----------
__global__ __launch_bounds__(256) void k_fill(const int* __restrict__ eidx,
                                              const int* __restrict__ nedges,
                                              unsigned* __restrict__ cursor,
                                              unsigned* __restrict__ csr) {
    int t = blockIdx.x * 256 + threadIdx.x;   // [0, B*E)
    int b = t >> 17;
    int e = t & (Ec - 1);
    if (e >= nedges[b]) return;
    int dst = eidx[(size_t)(b * 2 + 1) * Ec + e];
    unsigned pos = atomicAdd(&cursor[b * Nc + dst], 1u);
    csr[pos] = (unsigned)e;
}

// ---------- attention: one wave per node, online softmax, no atomics ----------
__global__ __launch_bounds__(256) void k_attn(const unsigned short* __restrict__ Q,
                                              const unsigned short* __restrict__ K,
                                              const unsigned short* __restrict__ V,
                                              const float* __restrict__ ef,
                                              const int* __restrict__ eidx,
                                              const unsigned* __restrict__ rowptr,
                                              const unsigned* __restrict__ csr,
                                              const float* __restrict__ We,
                                              float* __restrict__ attn) {
    int wave = threadIdx.x >> 6, lane = threadIdx.x & 63;
    int i = blockIdx.x * 4 + wave;            // node id in [0, BN)
    int b = i >> 14;                          // N = 16384 = 2^14
    int hh = lane >> 3;                       // head
    int j  = lane & 7;                        // 8 lanes per head, 2 elems each
    int col = hh * 16 + j * 2;

    // Q fragment (2 bf16)
    unsigned qv = *(const unsigned*)(Q + (size_t)i * 128 + col);
    float q0 = __uint_as_float(qv << 16);
    float q1 = __uint_as_float(qv & 0xFFFF0000u);
    float we0 = We[hh], we1 = We[8 + hh];

    unsigned p0 = rowptr[i], p1 = rowptr[i + 1];
    const int* srcArr = eidx + (size_t)(b * 2) * Ec;
    const unsigned short* Kb = K + (size_t)b * Nc * 128;
    const unsigned short* Vb = V + (size_t)b * Nc * 128;
    const float* efb = ef + (size_t)b * Ec * 2;

    float m = -INFINITY, l = 0.f, a0 = 0.f, a1 = 0.f;
    for (unsigned p = p0; p < p1; ++p) {
        int e = (int)csr[p];
        int src = srcArr[e];
        unsigned kv = *(const unsigned*)(Kb + (size_t)src * 128 + col);
        unsigned vv = *(const unsigned*)(Vb + (size_t)src * 128 + col);
        float k0 = __uint_as_float(kv << 16);
        float k1 = __uint_as_float(kv & 0xFFFF0000u);
        float dot = q0 * k0 + q1 * k1;
        dot += __shfl_xor(dot, 1, 64);
        dot += __shfl_xor(dot, 2, 64);
        dot += __shfl_xor(dot, 4, 64);        // all 8 head-lanes have full dot
        float lg = 0.25f * dot + efb[e * 2] * we0 + efb[e * 2 + 1] * we1;
        float nm = fmaxf(m, lg);
        float sc = __expf(m - nm);            // exp(-inf)=0 on first edge
        float pr = __expf(lg - nm);
        float v0 = __uint_as_float(vv << 16);
        float v1 = __uint_as_float(vv & 0xFFFF0000u);
        l  = l * sc + pr;
        a0 = a0 * sc + pr * v0;
        a1 = a1 * sc + pr * v1;
        m = nm;
    }
    float rcp = 1.f / fmaxf(l, 1e-6f);
    float2 o; o.x = a0 * rcp; o.y = a1 * rcp;
    *(float2*)(attn + (size_t)i * 128 + col) = o;
}

// ---------- out@Wo + bo + h  -> LN1 -> h1 (bf16) ----------
__global__ __launch_bounds__(256) void k_wo_ln(const float* __restrict__ attn,
                                               const float* __restrict__ Wo,
                                               const float* __restrict__ bo,
                                               const float* __restrict__ hin,
                                               const float* __restrict__ g,
                                               const float* __restrict__ bb,
                                               unsigned short* __restrict__ h1) {
    __shared__ unsigned short w[16384];
    stage_w_bf16(w, Wo, 4096);
    __syncthreads();
    int wave = threadIdx.x >> 6, lane = threadIdx.x & 63;
    size_t row = (size_t)blockIdx.x * 4 + wave;
    const float* a = attn + row * 128;
    float x0 = a[lane], x1 = a[64 + lane];
    float acc0 = 0.f, acc1 = 0.f;
#pragma unroll 1
    for (int half = 0; half < 2; ++half) {
        float xs = half ? x1 : x0;
        for (int k2 = 0; k2 < 64; ++k2) {
            float xb = __shfl(xs, k2, 64);
            int k = half * 64 + k2;
            acc0 += xb * b2f(w[(k << 7) + lane]);
            acc1 += xb * b2f(w[(k << 7) + 64 + lane]);
        }
    }
    acc0 += bo[lane]      + hin[row * 128 + lane];
    acc1 += bo[64 + lane] + hin[row * 128 + 64 + lane];
    float s1 = acc0 + acc1, s2 = acc0 * acc0 + acc1 * acc1;
#pragma unroll
    for (int o = 32; o > 0; o >>= 1) { s1 += __shfl_xor(s1, o, 64); s2 += __shfl_xor(s2, o, 64); }
    float mean = s1 * (1.f / 128.f);
    float var  = s2 * (1.f / 128.f) - mean * mean;
    float rstd = rsqrtf(var + 1e-5f);
    h1[row * 128 + lane]      = f2b((acc0 - mean) * rstd * g[lane] + bb[lane]);
    h1[row * 128 + 64 + lane] = f2b((acc1 - mean) * rstd * g[64 + lane] + bb[64 + lane]);
}

// ---------- mid = relu(h1@ff1 + b1) (bf16) ----------
__global__ __launch_bounds__(256) void k_ff1(const unsigned short* __restrict__ h1,
                                             const float* __restrict__ ff1,
                                             const float* __restrict__ b1,
                                             unsigned short* __restrict__ mid) {
    __shared__ unsigned short w[32768];  // 128x256 bf16 = 64KB
    stage_w_bf16(w, ff1, 8192);
    __syncthreads();
    int wave = threadIdx.x >> 6, lane = threadIdx.x & 63;
    size_t row = (size_t)blockIdx.x * 4 + wave;
    float x0 = b2f(h1[row * 128 + lane]);
    float x1 = b2f(h1[row * 128 + 64 + lane]);
    float acc[4] = {0.f, 0.f, 0.f, 0.f};
#pragma unroll 1
    for (int half = 0; half < 2; ++half) {
        float xs = half ? x1 : x0;
        for (int k2 = 0; k2 < 64; ++k2) {
            float xb = __shfl(xs, k2, 64);
            int k = half * 64 + k2;
#pragma unroll
            for (int jj = 0; jj < 4; ++jj) acc[jj] += xb * b2f(w[(k << 8) + (jj << 6) + lane]);
        }
    }
#pragma unroll
    for (int jj = 0; jj < 4; ++jj) {
        int c = (jj << 6) + lane;
        mid[row * 256 + c] = f2b(fmaxf(acc[jj] + b1[c], 0.f));
    }
}

// ---------- mid@ff2 + b2 + h1 -> LN2 -> out (f32) ----------
__global__ __launch_bounds__(256) void k_ff2_ln(const unsigned short* __restrict__ mid,
                                                const float* __restrict__ ff2,
                                                const float* __restrict__ b2p,
                                                const unsigned short* __restrict__ h1,
                                                const float* __restrict__ g,
                                                const float* __restrict__ bb,
                                                float* __restrict__ out) {
    __shared__ unsigned short w[32768];  // 256x128 bf16 = 64KB
    stage_w_bf16(w, ff2, 8192);
    __syncthreads();
    int wave = threadIdx.x >> 6, lane = threadIdx.x & 63;
    size_t row = (size_t)blockIdx.x * 4 + wave;
    float xs4[4];
#pragma unroll
    for (int jj = 0; jj < 4; ++jj) xs4[jj] = b2f(mid[row * 256 + (jj << 6) + lane]);
    float acc0 = 0.f, acc1 = 0.f;
#pragma unroll 1
    for (int q = 0; q < 4; ++q) {
        float xs = xs4[q];
        for (int k2 = 0; k2 < 64; ++k2) {
            float xb = __shfl(xs, k2, 64);
            int k = (q << 6) + k2;
            acc0 += xb * b2f(w[(k << 7) + lane]);
            acc1 += xb * b2f(w[(k << 7) + 64 + lane]);
        }
    }
    acc0 += b2p[lane]      + b2f(h1[row * 128 + lane]);
    acc1 += b2p[64 + lane] + b2f(h1[row * 128 + 64 + lane]);
    float s1 = acc0 + acc1, s2 = acc0 * acc0 + acc1 * acc1;
#pragma unroll
    for (int o = 32; o > 0; o >>= 1) { s1 += __shfl_xor(s1, o, 64); s2 += __shfl_xor(s2, o, 64); }
    float mean = s1 * (1.f / 128.f);
    float var  = s2 * (1.f / 128.f) - mean * mean;
    float rstd = rsqrtf(var + 1e-5f);
    out[row * 128 + lane]      = (acc0 - mean) * rstd * g[lane] + bb[lane];
    out[row * 128 + 64 + lane] = (acc1 - mean) * rstd * g[64 + lane] + bb[64 + lane];
}

extern "C" void kernel_launch(void* const* d_in, const int* in_sizes, int n_in,
                              void* d_out, int out_size, void* d_ws, size_t ws_size,
                              hipStream_t stream) {
    const float* h    = (const float*)d_in[0];
    const float* ef   = (const float*)d_in[1];
    const int*   eidx = (const int*)d_in[2];
    const int*   ne   = (const int*)d_in[3];
    const float* Wq   = (const float*)d_in[4];
    const float* Wk   = (const float*)d_in[5];
    const float* Wv   = (const float*)d_in[6];
    const float* Wo   = (const float*)d_in[7];
    const float* bo   = (const float*)d_in[8];
    const float* We   = (const float*)d_in[9];
    const float* ln1g = (const float*)d_in[10];
    const float* ln1b = (const float*)d_in[11];
    const float* ln2g = (const float*)d_in[12];
    const float* ln2b = (const float*)d_in[13];
    const float* ff1  = (const float*)d_in[14];
    const float* b1   = (const float*)d_in[15];
    const float* ff2  = (const float*)d_in[16];
    const float* b2   = (const float*)d_in[17];

    constexpr size_t MB = 1024 * 1024;
    char* ws = (char*)d_ws;
    unsigned short* Q       = (unsigned short*)(ws + 0 * MB);    // 16 MB bf16
    unsigned short* Kp      = (unsigned short*)(ws + 16 * MB);   // 16 MB bf16
    unsigned short* V       = (unsigned short*)(ws + 32 * MB);   // 16 MB bf16
    float*          attn    = (float*)(ws + 48 * MB);            // 32 MB f32
    unsigned short* h1      = (unsigned short*)(ws + 80 * MB);   // 16 MB bf16
    unsigned short* mid     = (unsigned short*)(ws + 96 * MB);   // 32 MB bf16
    unsigned*       counts  = (unsigned*)(ws + 128 * MB);        // 256 KB
    unsigned*       rowptr  = (unsigned*)(ws + 129 * MB);        // 256 KB + 4
    unsigned*       cursor  = (unsigned*)(ws + 130 * MB);        // 256 KB
    unsigned*       bsum    = (unsigned*)(ws + 131 * MB);        // 1 KB
    unsigned*       csr     = (unsigned*)(ws + 132 * MB);        // 2 MB

    const int rowBlocks  = (Bc * Nc) / 4;        // 16384
    const int edgeBlocks = (Bc * Ec) / 256;      // 2048
    const int scanBlocks = BN / 256;             // 256

    k_init<<<scanBlocks, 256, 0, stream>>>(counts);
    k_qkv<<<dim3(rowBlocks, 3), 256, 0, stream>>>(h, Wq, Wk, Wv, Q, Kp, V);
    k_hist<<<edgeBlocks, 256, 0, stream>>>(eidx, ne, counts);
    k_scan1<<<scanBlocks, 256, 0, stream>>>(counts, rowptr, bsum);
    k_scan2<<<1, 256, 0, stream>>>(bsum);
    k_scan3<<<scanBlocks, 256, 0, stream>>>(rowptr, bsum, counts, cursor);
    k_fill<<<edgeBlocks, 256, 0, stream>>>(eidx, ne, cursor, csr);
    k_attn<<<BN / 4, 256, 0, stream>>>(Q, Kp, V, ef, eidx, rowptr, csr, We, attn);
    k_wo_ln<<<rowBlocks, 256, 0, stream>>>(attn, Wo, bo, h, ln1g, ln1b, h1);
    k_ff1<<<rowBlocks, 256, 0, stream>>>(h1, ff1, b1, mid);
    k_ff2_ln<<<rowBlocks, 256, 0, stream>>>(mid, ff2, b2, h1, ln2g, ln2b,
                                            (float*)d_out);
}

// Round 4
// 363.404 us; speedup vs baseline: 12.4598x; 4.0344x over previous
//
#include <hip/hip_runtime.h>
#include <string.h>

// Problem constants
constexpr int Bc   = 4;
constexpr int Nc   = 16384;
constexpr int Ec   = 131072;   // 2^17
constexpr int Hc   = 8;
constexpr int Dc   = 16;
constexpr int HIDc = 128;
constexpr int BN   = Bc * Nc;  // 65536

// R3 post-mortem: shuffle-GEMMs (VALUBusy 46%, MfmaUtil 0) ran at ~12 TF.
// R4: all four dense GEMMs -> mfma_f32_16x16x32_bf16. Weight staged in LDS
// transposed + XOR-swizzled (chunk c^(n&7)) so B-fragments are ds_read_b128
// with free 2-way conflicts; A-fragments straight from global; LN/ReLU
// epilogues fused (C-layout: col=lane&15, row=quad*4+reg -> row stats via
// 16-lane shfl_xor). CSR + register online-softmax attention unchanged.

typedef __bf16 bf16_t;
typedef bf16_t bf16x8 __attribute__((ext_vector_type(8)));
typedef float  f32x4  __attribute__((ext_vector_type(4)));

union BF8 { bf16x8 v; uint4 u; unsigned short s[8]; };

// ---------- helpers ----------
__device__ inline float b2f(unsigned short u) {
    return __uint_as_float(((unsigned)u) << 16);
}
__device__ inline unsigned short f2b(float f) {
    unsigned b = __float_as_uint(f);
    unsigned r = (b + 0x7FFFu + ((b >> 16) & 1u)) >> 16;  // RNE
    return (unsigned short)r;
}

// ---------- unified MFMA GEMM: C[row][col] = A[row][0:KD] @ W[0:KD][col] ----------
// KD: inner dim (128 or 256). AF32: A is f32 (else bf16). EPI:
//   0 = plain bf16 store
//   1 = bias + relu, bf16 store
//   2 = bias + residual(f32) + LN, bf16 store
//   3 = bias + residual(bf16) + LN, f32 store
// N per block = 128 (8 n-tiles); 4 waves x 16 rows x 4 m-iters = 256 rows/block.
template<int KD, bool AF32, int EPI>
__global__ __launch_bounds__(256) void k_gemm(const void* __restrict__ Ap,
                                              const float* __restrict__ W, int wPitch,
                                              const float* __restrict__ bias,
                                              const void* __restrict__ resid,
                                              const float* __restrict__ g,
                                              const float* __restrict__ bb,
                                              void* __restrict__ Out, int oPitch) {
    constexpr int CHUNKS = KD / 8;            // 16B chunks per LDS row
    constexpr int KS     = KD / 32;           // MFMA k-steps
    __shared__ unsigned short wt[128 * KD];   // 32KB (KD=128) or 64KB (KD=256)

    // ---- stage W transposed+swizzled: wt[n][ (c^(n&7))*8 .. ] = W[c*8..][n] ----
    const int wcol0 = blockIdx.y * 128;
    for (int idx = threadIdx.x; idx < 128 * CHUNKS; idx += 256) {
        int n = idx & 127;
        int c = idx >> 7;
        BF8 pk;
#pragma unroll
        for (int j = 0; j < 8; ++j)
            pk.v[j] = (bf16_t)W[(size_t)(c * 8 + j) * wPitch + wcol0 + n];
        *(uint4*)&wt[n * KD + (c ^ (n & 7)) * 8] = pk.u;
    }
    __syncthreads();

    const int wave = threadIdx.x >> 6, lane = threadIdx.x & 63;
    const int nn = lane & 15, q = lane >> 4;

#pragma unroll 1
    for (int it = 0; it < 4; ++it) {
        const int row0 = (blockIdx.x * 4 + it) * 64 + wave * 16;
        const int arow = row0 + nn;           // A-operand: m = lane&15

        // ---- A fragments: A[m][k = ks*32 + q*8 + j] ----
        bf16x8 afrag[KS];
        if constexpr (AF32) {
            const float* A = (const float*)Ap + (size_t)arow * KD;
#pragma unroll
            for (int ks = 0; ks < KS; ++ks) {
                int k0 = ks * 32 + q * 8;
                float4 f0 = *(const float4*)(A + k0);
                float4 f1 = *(const float4*)(A + k0 + 4);
                BF8 pk;
                pk.v[0] = (bf16_t)f0.x; pk.v[1] = (bf16_t)f0.y;
                pk.v[2] = (bf16_t)f0.z; pk.v[3] = (bf16_t)f0.w;
                pk.v[4] = (bf16_t)f1.x; pk.v[5] = (bf16_t)f1.y;
                pk.v[6] = (bf16_t)f1.z; pk.v[7] = (bf16_t)f1.w;
                afrag[ks] = pk.v;
            }
        } else {
            const unsigned short* A = (const unsigned short*)Ap + (size_t)arow * KD;
#pragma unroll
            for (int ks = 0; ks < KS; ++ks) {
                BF8 pk;
                pk.u = *(const uint4*)(A + ks * 32 + q * 8);
                afrag[ks] = pk.v;
            }
        }

        // ---- MFMA over 8 n-tiles ----
        f32x4 acc[8];
#pragma unroll
        for (int nt = 0; nt < 8; ++nt) acc[nt] = (f32x4){0.f, 0.f, 0.f, 0.f};
#pragma unroll
        for (int nt = 0; nt < 8; ++nt) {
            int n = nt * 16 + nn;             // B-operand: n = lane&15
#pragma unroll
            for (int ks = 0; ks < KS; ++ks) {
                int c = ks * 4 + q;           // B k-chunk = ks*32 + q*8
                BF8 bf;
                bf.u = *(const uint4*)&wt[n * KD + (c ^ (n & 7)) * 8];
                acc[nt] = __builtin_amdgcn_mfma_f32_16x16x32_bf16(afrag[ks], bf.v,
                                                                  acc[nt], 0, 0, 0);
            }
        }

        // ---- epilogue (C/D layout: col = nt*16+nn, row = row0 + q*4 + reg) ----
        if constexpr (EPI == 0) {
            unsigned short* O = (unsigned short*)Out;
#pragma unroll
            for (int nt = 0; nt < 8; ++nt) {
                int col = blockIdx.y * 128 + nt * 16 + nn;
#pragma unroll
                for (int r = 0; r < 4; ++r)
                    O[(size_t)(row0 + q * 4 + r) * oPitch + col] = f2b(acc[nt][r]);
            }
        } else if constexpr (EPI == 1) {
            unsigned short* O = (unsigned short*)Out;
#pragma unroll
            for (int nt = 0; nt < 8; ++nt) {
                int col = blockIdx.y * 128 + nt * 16 + nn;
                float bv = bias[col];
#pragma unroll
                for (int r = 0; r < 4; ++r)
                    O[(size_t)(row0 + q * 4 + r) * oPitch + col] =
                        f2b(fmaxf(acc[nt][r] + bv, 0.f));
            }
        } else {
            // LN variants (full N=128 in-block; y == 0)
            float rs[4] = {0.f, 0.f, 0.f, 0.f}, rq[4] = {0.f, 0.f, 0.f, 0.f};
#pragma unroll
            for (int nt = 0; nt < 8; ++nt) {
                int col = nt * 16 + nn;
                float bv = bias[col];
#pragma unroll
                for (int r = 0; r < 4; ++r) {
                    int row = row0 + q * 4 + r;
                    float res;
                    if constexpr (EPI == 2)
                        res = ((const float*)resid)[(size_t)row * 128 + col];
                    else
                        res = b2f(((const unsigned short*)resid)[(size_t)row * 128 + col]);
                    float x = acc[nt][r] + bv + res;
                    acc[nt][r] = x;
                    rs[r] += x; rq[r] += x * x;
                }
            }
#pragma unroll
            for (int r = 0; r < 4; ++r) {
#pragma unroll
                for (int o = 1; o < 16; o <<= 1) {
                    rs[r] += __shfl_xor(rs[r], o, 64);
                    rq[r] += __shfl_xor(rq[r], o, 64);
                }
            }
            float mean[4], rstd[4];
#pragma unroll
            for (int r = 0; r < 4; ++r) {
                mean[r] = rs[r] * (1.f / 128.f);
                float var = rq[r] * (1.f / 128.f) - mean[r] * mean[r];
                rstd[r] = rsqrtf(var + 1e-5f);
            }
#pragma unroll
            for (int nt = 0; nt < 8; ++nt) {
                int col = nt * 16 + nn;
                float gv = g[col], bv2 = bb[col];
#pragma unroll
                for (int r = 0; r < 4; ++r) {
                    int row = row0 + q * 4 + r;
                    float y = (acc[nt][r] - mean[r]) * rstd[r] * gv + bv2;
                    if constexpr (EPI == 2)
                        ((unsigned short*)Out)[(size_t)row * 128 + col] = f2b(y);
                    else
                        ((float*)Out)[(size_t)row * 128 + col] = y;
                }
            }
        }
    }
}

// ---------- init: zero histogram counters ----------
__global__ __launch_bounds__(256) void k_init(unsigned* __restrict__ counts) {
    int i = blockIdx.x * 256 + threadIdx.x;   // grid covers BN
    counts[i] = 0u;
}

// ---------- CSR build: histogram of dst ----------
__global__ __launch_bounds__(256) void k_hist(const int* __restrict__ eidx,
                                              const int* __restrict__ nedges,
                                              unsigned* __restrict__ counts) {
    int t = blockIdx.x * 256 + threadIdx.x;   // [0, B*E)
    int b = t >> 17;
    int e = t & (Ec - 1);
    if (e >= nedges[b]) return;
    int dst = eidx[(size_t)(b * 2 + 1) * Ec + e];
    atomicAdd(&counts[b * Nc + dst], 1u);
}

// ---------- scan step 1: per-block (256) exclusive scan + block sums ----------
__global__ __launch_bounds__(256) void k_scan1(const unsigned* __restrict__ counts,
                                               unsigned* __restrict__ rowptr,
                                               unsigned* __restrict__ bsum) {
    __shared__ unsigned s[256];
    int t = threadIdx.x;
    int i = blockIdx.x * 256 + t;
    unsigned own = counts[i];
    s[t] = own;
    __syncthreads();
#pragma unroll
    for (int off = 1; off < 256; off <<= 1) {
        unsigned v = (t >= off) ? s[t - off] : 0u;
        __syncthreads();
        s[t] += v;
        __syncthreads();
    }
    rowptr[i] = s[t] - own;            // exclusive within block
    if (t == 255) bsum[blockIdx.x] = s[255];
}

// ---------- scan step 2: exclusive scan of 256 block sums ----------
__global__ __launch_bounds__(256) void k_scan2(unsigned* __restrict__ bsum) {
    __shared__ unsigned s[256];
    int t = threadIdx.x;
    unsigned own = bsum[t];
    s[t] = own;
    __syncthreads();
#pragma unroll
    for (int off = 1; off < 256; off <<= 1) {
        unsigned v = (t >= off) ? s[t - off] : 0u;
        __syncthreads();
        s[t] += v;
        __syncthreads();
    }
    bsum[t] = s[t] - own;
}

// ---------- scan step 3: add block offsets, copy to cursor, set tail ----------
__global__ __launch_bounds__(256) void k_scan3(unsigned* __restrict__ rowptr,
                                               const unsigned* __restrict__ bsum,
                                               const unsigned* __restrict__ counts,
                                               unsigned* __restrict__ cursor) {
    int i = blockIdx.x * 256 + threadIdx.x;
    unsigned v = rowptr[i] + bsum[blockIdx.x];
    rowptr[i] = v;
    cursor[i] = v;
    if (i == BN - 1) rowptr[BN] = v + counts[i];
}

// ---------- CSR fill ----------
__global__ __launch_bounds__(256) void k_fill(const int* __restrict__ eidx,
                                              const int* __restrict__ nedges,
                                              unsigned* __restrict__ cursor,
                                              unsigned* __restrict__ csr) {
    int t = blockIdx.x * 256 + threadIdx.x;   // [0, B*E)
    int b = t >> 17;
    int e = t & (Ec - 1);
    if (e >= nedges[b]) return;
    int dst = eidx[(size_t)(b * 2 + 1) * Ec + e];
    unsigned pos = atomicAdd(&cursor[b * Nc + dst], 1u);
    csr[pos] = (unsigned)e;
}

// ---------- attention: one wave per node, online softmax, no atomics ----------
__global__ __launch_bounds__(256) void k_attn(const unsigned short* __restrict__ Q,
                                              const unsigned short* __restrict__ K,
                                              const unsigned short* __restrict__ V,
                                              const float* __restrict__ ef,
                                              const int* __restrict__ eidx,
                                              const unsigned* __restrict__ rowptr,
                                              const unsigned* __restrict__ csr,
                                              const float* __restrict__ We,
                                              float* __restrict__ attn) {
    int wave = threadIdx.x >> 6, lane = threadIdx.x & 63;
    int i = blockIdx.x * 4 + wave;            // node id in [0, BN)
    int b = i >> 14;                          // N = 16384 = 2^14
    int hh = lane >> 3;                       // head
    int j  = lane & 7;                        // 8 lanes per head, 2 elems each
    int col = hh * 16 + j * 2;

    unsigned qv = *(const unsigned*)(Q + (size_t)i * 128 + col);
    float q0 = __uint_as_float(qv << 16);
    float q1 = __uint_as_float(qv & 0xFFFF0000u);
    float we0 = We[hh], we1 = We[8 + hh];

    unsigned p0 = rowptr[i], p1 = rowptr[i + 1];
    const int* srcArr = eidx + (size_t)(b * 2) * Ec;
    const unsigned short* Kb = K + (size_t)b * Nc * 128;
    const unsigned short* Vb = V + (size_t)b * Nc * 128;
    const float* efb = ef + (size_t)b * Ec * 2;

    float m = -INFINITY, l = 0.f, a0 = 0.f, a1 = 0.f;
    for (unsigned p = p0; p < p1; ++p) {
        int e = (int)csr[p];
        int src = srcArr[e];
        unsigned kv = *(const unsigned*)(Kb + (size_t)src * 128 + col);
        unsigned vv = *(const unsigned*)(Vb + (size_t)src * 128 + col);
        float k0 = __uint_as_float(kv << 16);
        float k1 = __uint_as_float(kv & 0xFFFF0000u);
        float dot = q0 * k0 + q1 * k1;
        dot += __shfl_xor(dot, 1, 64);
        dot += __shfl_xor(dot, 2, 64);
        dot += __shfl_xor(dot, 4, 64);        // all 8 head-lanes have full dot
        float lg = 0.25f * dot + efb[e * 2] * we0 + efb[e * 2 + 1] * we1;
        float nm = fmaxf(m, lg);
        float sc = __expf(m - nm);            // exp(-inf)=0 on first edge
        float pr = __expf(lg - nm);
        float v0 = __uint_as_float(vv << 16);
        float v1 = __uint_as_float(vv & 0xFFFF0000u);
        l  = l * sc + pr;
        a0 = a0 * sc + pr * v0;
        a1 = a1 * sc + pr * v1;
        m = nm;
    }
    float rcp = 1.f / fmaxf(l, 1e-6f);
    float2 o; o.x = a0 * rcp; o.y = a1 * rcp;
    *(float2*)(attn + (size_t)i * 128 + col) = o;
}

extern "C" void kernel_launch(void* const* d_in, const int* in_sizes, int n_in,
                              void* d_out, int out_size, void* d_ws, size_t ws_size,
                              hipStream_t stream) {
    const float* h    = (const float*)d_in[0];
    const float* ef   = (const float*)d_in[1];
    const int*   eidx = (const int*)d_in[2];
    const int*   ne   = (const int*)d_in[3];
    const float* Wq   = (const float*)d_in[4];
    const float* Wk   = (const float*)d_in[5];
    const float* Wv   = (const float*)d_in[6];
    const float* Wo   = (const float*)d_in[7];
    const float* bo   = (const float*)d_in[8];
    const float* We   = (const float*)d_in[9];
    const float* ln1g = (const float*)d_in[10];
    const float* ln1b = (const float*)d_in[11];
    const float* ln2g = (const float*)d_in[12];
    const float* ln2b = (const float*)d_in[13];
    const float* ff1  = (const float*)d_in[14];
    const float* b1   = (const float*)d_in[15];
    const float* ff2  = (const float*)d_in[16];
    const float* b2   = (const float*)d_in[17];

    constexpr size_t MB = 1024 * 1024;
    char* ws = (char*)d_ws;
    unsigned short* Q       = (unsigned short*)(ws + 0 * MB);    // 16 MB bf16
    unsigned short* Kp      = (unsigned short*)(ws + 16 * MB);   // 16 MB bf16
    unsigned short* V       = (unsigned short*)(ws + 32 * MB);   // 16 MB bf16
    float*          attn    = (float*)(ws + 48 * MB);            // 32 MB f32
    unsigned short* h1      = (unsigned short*)(ws + 80 * MB);   // 16 MB bf16
    unsigned short* mid     = (unsigned short*)(ws + 96 * MB);   // 32 MB bf16
    unsigned*       counts  = (unsigned*)(ws + 128 * MB);        // 256 KB
    unsigned*       rowptr  = (unsigned*)(ws + 129 * MB);        // 256 KB + 4
    unsigned*       cursor  = (unsigned*)(ws + 130 * MB);        // 256 KB
    unsigned*       bsum    = (unsigned*)(ws + 131 * MB);        // 1 KB
    unsigned*       csr     = (unsigned*)(ws + 132 * MB);        // 2 MB

    const int edgeBlocks = (Bc * Ec) / 256;      // 2048
    const int scanBlocks = BN / 256;             // 256
    const int gemmBlocks = BN / 256;             // 256 (4 m-iters of 64 rows each)

    // CSR build
    k_init<<<scanBlocks, 256, 0, stream>>>(counts);
    k_hist<<<edgeBlocks, 256, 0, stream>>>(eidx, ne, counts);
    k_scan1<<<scanBlocks, 256, 0, stream>>>(counts, rowptr, bsum);
    k_scan2<<<1, 256, 0, stream>>>(bsum);
    k_scan3<<<scanBlocks, 256, 0, stream>>>(rowptr, bsum, counts, cursor);
    k_fill<<<edgeBlocks, 256, 0, stream>>>(eidx, ne, cursor, csr);

    // QKV projections (MFMA)
    k_gemm<128, true, 0><<<dim3(gemmBlocks, 1), 256, 0, stream>>>(
        h, Wq, 128, nullptr, nullptr, nullptr, nullptr, Q, 128);
    k_gemm<128, true, 0><<<dim3(gemmBlocks, 1), 256, 0, stream>>>(
        h, Wk, 128, nullptr, nullptr, nullptr, nullptr, Kp, 128);
    k_gemm<128, true, 0><<<dim3(gemmBlocks, 1), 256, 0, stream>>>(
        h, Wv, 128, nullptr, nullptr, nullptr, nullptr, V, 128);

    // Attention
    k_attn<<<BN / 4, 256, 0, stream>>>(Q, Kp, V, ef, eidx, rowptr, csr, We, attn);

    // Wo + bo + residual + LN1 -> h1 (bf16)
    k_gemm<128, true, 2><<<dim3(gemmBlocks, 1), 256, 0, stream>>>(
        attn, Wo, 128, bo, h, ln1g, ln1b, h1, 128);

    // ff1 + b1 + relu -> mid (bf16), two 128-col halves
    k_gemm<128, false, 1><<<dim3(gemmBlocks, 2), 256, 0, stream>>>(
        h1, ff1, 256, b1, nullptr, nullptr, nullptr, mid, 256);

    // ff2 + b2 + residual(h1) + LN2 -> out (f32)
    k_gemm<256, false, 3><<<dim3(gemmBlocks, 1), 256, 0, stream>>>(
        mid, ff2, 128, b2, h1, ln2g, ln2b, d_out, 128);
}

// Round 5
// 333.678 us; speedup vs baseline: 13.5698x; 1.0891x over previous
//
#include <hip/hip_runtime.h>
#include <string.h>

// Problem constants
constexpr int Bc   = 4;
constexpr int Nc   = 16384;
constexpr int Ec   = 131072;   // 2^17
constexpr int Hc   = 8;
constexpr int Dc   = 16;
constexpr int HIDc = 128;
constexpr int BN   = Bc * Nc;  // 65536

// R4 post-mortem: k_attn (87us) latency-bound: serial csr->src->K/V chain,
// mean degree ~4-8, neither VALU (38%) nor HBM (22%) saturated.
// R5: edge loop unrolled x4 (batched independent loads, single rescale per
// batch); attn intermediate f32->bf16 (halves its write+read); GEMM blocks
// 256->512 (2 m-iters) for 2 blocks/CU so staging overlaps compute.

typedef __bf16 bf16_t;
typedef bf16_t bf16x8 __attribute__((ext_vector_type(8)));
typedef float  f32x4  __attribute__((ext_vector_type(4)));

union BF8 { bf16x8 v; uint4 u; unsigned short s[8]; };

// ---------- helpers ----------
__device__ inline float b2f(unsigned short u) {
    return __uint_as_float(((unsigned)u) << 16);
}
__device__ inline unsigned short f2b(float f) {
    unsigned b = __float_as_uint(f);
    unsigned r = (b + 0x7FFFu + ((b >> 16) & 1u)) >> 16;  // RNE
    return (unsigned short)r;
}
__device__ inline float lo16(unsigned u) { return __uint_as_float(u << 16); }
__device__ inline float hi16(unsigned u) { return __uint_as_float(u & 0xFFFF0000u); }

// ---------- unified MFMA GEMM ----------
// KD: inner dim (128/256). AF32: A f32 (else bf16). ITERS: 64-row m-iters per
// block. EPI: 0 plain bf16; 1 bias+relu bf16; 2 bias+resid(f32)+LN bf16;
// 3 bias+resid(bf16)+LN f32.
template<int KD, bool AF32, int EPI, int ITERS>
__global__ __launch_bounds__(256) void k_gemm(const void* __restrict__ Ap,
                                              const float* __restrict__ W, int wPitch,
                                              const float* __restrict__ bias,
                                              const void* __restrict__ resid,
                                              const float* __restrict__ g,
                                              const float* __restrict__ bb,
                                              void* __restrict__ Out, int oPitch) {
    constexpr int CHUNKS = KD / 8;
    constexpr int KS     = KD / 32;
    __shared__ unsigned short wt[128 * KD];   // 32KB (KD=128) / 64KB (KD=256)

    // ---- stage W transposed+swizzled: wt[n][(c^(n&7))*8..] = W[c*8..][n] ----
    const int wcol0 = blockIdx.y * 128;
    for (int idx = threadIdx.x; idx < 128 * CHUNKS; idx += 256) {
        int n = idx & 127;
        int c = idx >> 7;
        BF8 pk;
#pragma unroll
        for (int j = 0; j < 8; ++j)
            pk.v[j] = (bf16_t)W[(size_t)(c * 8 + j) * wPitch + wcol0 + n];
        *(uint4*)&wt[n * KD + (c ^ (n & 7)) * 8] = pk.u;
    }
    __syncthreads();

    const int wave = threadIdx.x >> 6, lane = threadIdx.x & 63;
    const int nn = lane & 15, q = lane >> 4;

#pragma unroll 1
    for (int it = 0; it < ITERS; ++it) {
        const int row0 = (blockIdx.x * ITERS + it) * 64 + wave * 16;
        const int arow = row0 + nn;           // A-operand: m = lane&15

        bf16x8 afrag[KS];
        if constexpr (AF32) {
            const float* A = (const float*)Ap + (size_t)arow * KD;
#pragma unroll
            for (int ks = 0; ks < KS; ++ks) {
                int k0 = ks * 32 + q * 8;
                float4 f0 = *(const float4*)(A + k0);
                float4 f1 = *(const float4*)(A + k0 + 4);
                BF8 pk;
                pk.v[0] = (bf16_t)f0.x; pk.v[1] = (bf16_t)f0.y;
                pk.v[2] = (bf16_t)f0.z; pk.v[3] = (bf16_t)f0.w;
                pk.v[4] = (bf16_t)f1.x; pk.v[5] = (bf16_t)f1.y;
                pk.v[6] = (bf16_t)f1.z; pk.v[7] = (bf16_t)f1.w;
                afrag[ks] = pk.v;
            }
        } else {
            const unsigned short* A = (const unsigned short*)Ap + (size_t)arow * KD;
#pragma unroll
            for (int ks = 0; ks < KS; ++ks) {
                BF8 pk;
                pk.u = *(const uint4*)(A + ks * 32 + q * 8);
                afrag[ks] = pk.v;
            }
        }

        f32x4 acc[8];
#pragma unroll
        for (int nt = 0; nt < 8; ++nt) acc[nt] = (f32x4){0.f, 0.f, 0.f, 0.f};
#pragma unroll
        for (int nt = 0; nt < 8; ++nt) {
            int n = nt * 16 + nn;
#pragma unroll
            for (int ks = 0; ks < KS; ++ks) {
                int c = ks * 4 + q;
                BF8 bf;
                bf.u = *(const uint4*)&wt[n * KD + (c ^ (n & 7)) * 8];
                acc[nt] = __builtin_amdgcn_mfma_f32_16x16x32_bf16(afrag[ks], bf.v,
                                                                  acc[nt], 0, 0, 0);
            }
        }

        // ---- epilogue (C/D: col = nt*16+nn, row = row0 + q*4 + reg) ----
        if constexpr (EPI == 0) {
            unsigned short* O = (unsigned short*)Out;
#pragma unroll
            for (int nt = 0; nt < 8; ++nt) {
                int col = blockIdx.y * 128 + nt * 16 + nn;
#pragma unroll
                for (int r = 0; r < 4; ++r)
                    O[(size_t)(row0 + q * 4 + r) * oPitch + col] = f2b(acc[nt][r]);
            }
        } else if constexpr (EPI == 1) {
            unsigned short* O = (unsigned short*)Out;
#pragma unroll
            for (int nt = 0; nt < 8; ++nt) {
                int col = blockIdx.y * 128 + nt * 16 + nn;
                float bv = bias[col];
#pragma unroll
                for (int r = 0; r < 4; ++r)
                    O[(size_t)(row0 + q * 4 + r) * oPitch + col] =
                        f2b(fmaxf(acc[nt][r] + bv, 0.f));
            }
        } else {
            float rs[4] = {0.f, 0.f, 0.f, 0.f}, rq[4] = {0.f, 0.f, 0.f, 0.f};
#pragma unroll
            for (int nt = 0; nt < 8; ++nt) {
                int col = nt * 16 + nn;
                float bv = bias[col];
#pragma unroll
                for (int r = 0; r < 4; ++r) {
                    int row = row0 + q * 4 + r;
                    float res;
                    if constexpr (EPI == 2)
                        res = ((const float*)resid)[(size_t)row * 128 + col];
                    else
                        res = b2f(((const unsigned short*)resid)[(size_t)row * 128 + col]);
                    float x = acc[nt][r] + bv + res;
                    acc[nt][r] = x;
                    rs[r] += x; rq[r] += x * x;
                }
            }
#pragma unroll
            for (int r = 0; r < 4; ++r) {
#pragma unroll
                for (int o = 1; o < 16; o <<= 1) {
                    rs[r] += __shfl_xor(rs[r], o, 64);
                    rq[r] += __shfl_xor(rq[r], o, 64);
                }
            }
            float mean[4], rstd[4];
#pragma unroll
            for (int r = 0; r < 4; ++r) {
                mean[r] = rs[r] * (1.f / 128.f);
                float var = rq[r] * (1.f / 128.f) - mean[r] * mean[r];
                rstd[r] = rsqrtf(var + 1e-5f);
            }
#pragma unroll
            for (int nt = 0; nt < 8; ++nt) {
                int col = nt * 16 + nn;
                float gv = g[col], bv2 = bb[col];
#pragma unroll
                for (int r = 0; r < 4; ++r) {
                    int row = row0 + q * 4 + r;
                    float y = (acc[nt][r] - mean[r]) * rstd[r] * gv + bv2;
                    if constexpr (EPI == 2)
                        ((unsigned short*)Out)[(size_t)row * 128 + col] = f2b(y);
                    else
                        ((float*)Out)[(size_t)row * 128 + col] = y;
                }
            }
        }
    }
}

// ---------- init: zero histogram counters ----------
__global__ __launch_bounds__(256) void k_init(unsigned* __restrict__ counts) {
    int i = blockIdx.x * 256 + threadIdx.x;
    counts[i] = 0u;
}

// ---------- CSR build: histogram of dst ----------
__global__ __launch_bounds__(256) void k_hist(const int* __restrict__ eidx,
                                              const int* __restrict__ nedges,
                                              unsigned* __restrict__ counts) {
    int t = blockIdx.x * 256 + threadIdx.x;
    int b = t >> 17;
    int e = t & (Ec - 1);
    if (e >= nedges[b]) return;
    int dst = eidx[(size_t)(b * 2 + 1) * Ec + e];
    atomicAdd(&counts[b * Nc + dst], 1u);
}

// ---------- scan step 1 ----------
__global__ __launch_bounds__(256) void k_scan1(const unsigned* __restrict__ counts,
                                               unsigned* __restrict__ rowptr,
                                               unsigned* __restrict__ bsum) {
    __shared__ unsigned s[256];
    int t = threadIdx.x;
    int i = blockIdx.x * 256 + t;
    unsigned own = counts[i];
    s[t] = own;
    __syncthreads();
#pragma unroll
    for (int off = 1; off < 256; off <<= 1) {
        unsigned v = (t >= off) ? s[t - off] : 0u;
        __syncthreads();
        s[t] += v;
        __syncthreads();
    }
    rowptr[i] = s[t] - own;
    if (t == 255) bsum[blockIdx.x] = s[255];
}

// ---------- scan step 2 ----------
__global__ __launch_bounds__(256) void k_scan2(unsigned* __restrict__ bsum) {
    __shared__ unsigned s[256];
    int t = threadIdx.x;
    unsigned own = bsum[t];
    s[t] = own;
    __syncthreads();
#pragma unroll
    for (int off = 1; off < 256; off <<= 1) {
        unsigned v = (t >= off) ? s[t - off] : 0u;
        __syncthreads();
        s[t] += v;
        __syncthreads();
    }
    bsum[t] = s[t] - own;
}

// ---------- scan step 3 ----------
__global__ __launch_bounds__(256) void k_scan3(unsigned* __restrict__ rowptr,
                                               const unsigned* __restrict__ bsum,
                                               const unsigned* __restrict__ counts,
                                               unsigned* __restrict__ cursor) {
    int i = blockIdx.x * 256 + threadIdx.x;
    unsigned v = rowptr[i] + bsum[blockIdx.x];
    rowptr[i] = v;
    cursor[i] = v;
    if (i == BN - 1) rowptr[BN] = v + counts[i];
}

// ---------- CSR fill ----------
__global__ __launch_bounds__(256) void k_fill(const int* __restrict__ eidx,
                                              const int* __restrict__ nedges,
                                              unsigned* __restrict__ cursor,
                                              unsigned* __restrict__ csr) {
    int t = blockIdx.x * 256 + threadIdx.x;
    int b = t >> 17;
    int e = t & (Ec - 1);
    if (e >= nedges[b]) return;
    int dst = eidx[(size_t)(b * 2 + 1) * Ec + e];
    unsigned pos = atomicAdd(&cursor[b * Nc + dst], 1u);
    csr[pos] = (unsigned)e;
}

// ---------- attention: wave/node, online softmax, x4-unrolled edge loop ----------
__global__ __launch_bounds__(256) void k_attn(const unsigned short* __restrict__ Q,
                                              const unsigned short* __restrict__ K,
                                              const unsigned short* __restrict__ V,
                                              const float* __restrict__ ef,
                                              const int* __restrict__ eidx,
                                              const unsigned* __restrict__ rowptr,
                                              const unsigned* __restrict__ csr,
                                              const float* __restrict__ We,
                                              unsigned short* __restrict__ attn) {
    int wave = threadIdx.x >> 6, lane = threadIdx.x & 63;
    int i = blockIdx.x * 4 + wave;            // node id in [0, BN)
    int b = i >> 14;                          // N = 16384 = 2^14
    int hh = lane >> 3;                       // head
    int j  = lane & 7;                        // 8 lanes/head, 2 elems each
    int col = hh * 16 + j * 2;

    unsigned qv = *(const unsigned*)(Q + (size_t)i * 128 + col);
    float q0 = lo16(qv), q1 = hi16(qv);
    float we0 = We[hh], we1 = We[8 + hh];

    unsigned p0 = rowptr[i], p1 = rowptr[i + 1];
    const int* srcArr = eidx + (size_t)(b * 2) * Ec;
    const unsigned short* Kb = K + (size_t)b * Nc * 128;
    const unsigned short* Vb = V + (size_t)b * Nc * 128;
    const float* efb = ef + (size_t)b * Ec * 2;

    float m = -INFINITY, l = 0.f, a0 = 0.f, a1 = 0.f;
    unsigned p = p0;
    // ---- batched x4: all loads independent & in flight before any use ----
    for (; p + 4 <= p1; p += 4) {
        unsigned e4[4]; int s4[4]; unsigned kv[4], vv[4]; float2 f4[4];
#pragma unroll
        for (int u = 0; u < 4; ++u) e4[u] = csr[p + u];
#pragma unroll
        for (int u = 0; u < 4; ++u) s4[u] = srcArr[e4[u]];
#pragma unroll
        for (int u = 0; u < 4; ++u) {
            kv[u] = *(const unsigned*)(Kb + (size_t)s4[u] * 128 + col);
            vv[u] = *(const unsigned*)(Vb + (size_t)s4[u] * 128 + col);
            f4[u] = *(const float2*)(efb + (size_t)e4[u] * 2);
        }
        float lg[4];
#pragma unroll
        for (int u = 0; u < 4; ++u) {
            float d = q0 * lo16(kv[u]) + q1 * hi16(kv[u]);
            d += __shfl_xor(d, 1, 64);
            d += __shfl_xor(d, 2, 64);
            d += __shfl_xor(d, 4, 64);
            lg[u] = 0.25f * d + f4[u].x * we0 + f4[u].y * we1;
        }
        float M = fmaxf(fmaxf(fmaxf(lg[0], lg[1]), fmaxf(lg[2], lg[3])), m);
        float sc = __expf(m - M);
        float pr[4];
#pragma unroll
        for (int u = 0; u < 4; ++u) pr[u] = __expf(lg[u] - M);
        l  = l * sc + ((pr[0] + pr[1]) + (pr[2] + pr[3]));
        a0 = a0 * sc + pr[0] * lo16(vv[0]) + pr[1] * lo16(vv[1])
                     + pr[2] * lo16(vv[2]) + pr[3] * lo16(vv[3]);
        a1 = a1 * sc + pr[0] * hi16(vv[0]) + pr[1] * hi16(vv[1])
                     + pr[2] * hi16(vv[2]) + pr[3] * hi16(vv[3]);
        m = M;
    }
    // ---- remainder ----
    for (; p < p1; ++p) {
        int e = (int)csr[p];
        int src = srcArr[e];
        unsigned kv = *(const unsigned*)(Kb + (size_t)src * 128 + col);
        unsigned vv = *(const unsigned*)(Vb + (size_t)src * 128 + col);
        float2 f2v = *(const float2*)(efb + (size_t)e * 2);
        float d = q0 * lo16(kv) + q1 * hi16(kv);
        d += __shfl_xor(d, 1, 64);
        d += __shfl_xor(d, 2, 64);
        d += __shfl_xor(d, 4, 64);
        float lg = 0.25f * d + f2v.x * we0 + f2v.y * we1;
        float nm = fmaxf(m, lg);
        float sc = __expf(m - nm);
        float pr = __expf(lg - nm);
        l  = l * sc + pr;
        a0 = a0 * sc + pr * lo16(vv);
        a1 = a1 * sc + pr * hi16(vv);
        m = nm;
    }
    float rcp = 1.f / fmaxf(l, 1e-6f);
    unsigned pack = (unsigned)f2b(a0 * rcp) | ((unsigned)f2b(a1 * rcp) << 16);
    *(unsigned*)(attn + (size_t)i * 128 + col) = pack;
}

extern "C" void kernel_launch(void* const* d_in, const int* in_sizes, int n_in,
                              void* d_out, int out_size, void* d_ws, size_t ws_size,
                              hipStream_t stream) {
    const float* h    = (const float*)d_in[0];
    const float* ef   = (const float*)d_in[1];
    const int*   eidx = (const int*)d_in[2];
    const int*   ne   = (const int*)d_in[3];
    const float* Wq   = (const float*)d_in[4];
    const float* Wk   = (const float*)d_in[5];
    const float* Wv   = (const float*)d_in[6];
    const float* Wo   = (const float*)d_in[7];
    const float* bo   = (const float*)d_in[8];
    const float* We   = (const float*)d_in[9];
    const float* ln1g = (const float*)d_in[10];
    const float* ln1b = (const float*)d_in[11];
    const float* ln2g = (const float*)d_in[12];
    const float* ln2b = (const float*)d_in[13];
    const float* ff1  = (const float*)d_in[14];
    const float* b1   = (const float*)d_in[15];
    const float* ff2  = (const float*)d_in[16];
    const float* b2   = (const float*)d_in[17];

    constexpr size_t MB = 1024 * 1024;
    char* ws = (char*)d_ws;
    unsigned short* Q       = (unsigned short*)(ws + 0 * MB);    // 16 MB bf16
    unsigned short* Kp      = (unsigned short*)(ws + 16 * MB);   // 16 MB bf16
    unsigned short* V       = (unsigned short*)(ws + 32 * MB);   // 16 MB bf16
    unsigned short* attn    = (unsigned short*)(ws + 48 * MB);   // 16 MB bf16
    unsigned short* h1      = (unsigned short*)(ws + 64 * MB);   // 16 MB bf16
    unsigned short* mid     = (unsigned short*)(ws + 80 * MB);   // 32 MB bf16
    unsigned*       counts  = (unsigned*)(ws + 112 * MB);        // 256 KB
    unsigned*       rowptr  = (unsigned*)(ws + 113 * MB);        // 256 KB + 4
    unsigned*       cursor  = (unsigned*)(ws + 114 * MB);        // 256 KB
    unsigned*       bsum    = (unsigned*)(ws + 115 * MB);        // 1 KB
    unsigned*       csr     = (unsigned*)(ws + 116 * MB);        // 2 MB

    const int edgeBlocks = (Bc * Ec) / 256;      // 2048
    const int scanBlocks = BN / 256;             // 256
    const int gemmBlocks = BN / 128;             // 512 (2 m-iters of 64 rows)

    // CSR build
    k_init<<<scanBlocks, 256, 0, stream>>>(counts);
    k_hist<<<edgeBlocks, 256, 0, stream>>>(eidx, ne, counts);
    k_scan1<<<scanBlocks, 256, 0, stream>>>(counts, rowptr, bsum);
    k_scan2<<<1, 256, 0, stream>>>(bsum);
    k_scan3<<<scanBlocks, 256, 0, stream>>>(rowptr, bsum, counts, cursor);
    k_fill<<<edgeBlocks, 256, 0, stream>>>(eidx, ne, cursor, csr);

    // QKV projections (MFMA)
    k_gemm<128, true, 0, 2><<<dim3(gemmBlocks, 1), 256, 0, stream>>>(
        h, Wq, 128, nullptr, nullptr, nullptr, nullptr, Q, 128);
    k_gemm<128, true, 0, 2><<<dim3(gemmBlocks, 1), 256, 0, stream>>>(
        h, Wk, 128, nullptr, nullptr, nullptr, nullptr, Kp, 128);
    k_gemm<128, true, 0, 2><<<dim3(gemmBlocks, 1), 256, 0, stream>>>(
        h, Wv, 128, nullptr, nullptr, nullptr, nullptr, V, 128);

    // Attention (bf16 out)
    k_attn<<<BN / 4, 256, 0, stream>>>(Q, Kp, V, ef, eidx, rowptr, csr, We, attn);

    // Wo + bo + residual(h,f32) + LN1 -> h1 (bf16); A = attn (bf16)
    k_gemm<128, false, 2, 2><<<dim3(gemmBlocks, 1), 256, 0, stream>>>(
        attn, Wo, 128, bo, h, ln1g, ln1b, h1, 128);

    // ff1 + b1 + relu -> mid (bf16), two 128-col halves
    k_gemm<128, false, 1, 2><<<dim3(gemmBlocks, 2), 256, 0, stream>>>(
        h1, ff1, 256, b1, nullptr, nullptr, nullptr, mid, 256);

    // ff2 + b2 + residual(h1,bf16) + LN2 -> out (f32)
    k_gemm<256, false, 3, 2><<<dim3(gemmBlocks, 1), 256, 0, stream>>>(
        mid, ff2, 128, b2, h1, ln2g, ln2b, d_out, 128);
}